// Round 15
// baseline (1294.815 us; speedup 1.0000x reference)
//
#include <hip/hip_runtime.h>
#include <hip/hip_bf16.h>

typedef unsigned short u16;
typedef unsigned int u32;
typedef unsigned long long u64;
typedef __attribute__((ext_vector_type(8))) short short8;
typedef __attribute__((ext_vector_type(4))) float f32x4;

#define NB 256
#define NT 512          // 8 waves
#define TS 128

// d_out offsets (floats): [out][h_n0][h_n1][c_n0][c_n1]
#define OFF_H0  786432
#define OFF_H1  1048576
#define OFF_C0  1114112
#define OFF_C1  1376256

// ws layout (bytes)
#define WSO_W0F  0                          // 10,485,760
#define WSO_W1F  (WSO_W0F + 10485760)       // 2,621,440
#define WSO_B0   (WSO_W1F + 2621440)        // 16,384
#define WSO_B1   (WSO_B0  + 16384)          // 4,096
#define WSO_BAR  (WSO_B1  + 4096)
#define BAR_DW   (4096 + 64)                // flags 256x16dw + rel 4x16dw
#define WSO_H0   (WSO_BAR + BAR_DW*4)
#define H0SEQ_BYTES (129*524288)            // 129 panels [256][1024] bf16
#define WSO_H1   (WSO_H0 + H0SEQ_BYTES)
#define H1SEQ_BYTES (129*131072)            // 129 panels [256][256] bf16
#define WS_NEED  (WSO_H1 + H1SEQ_BYTES)     // ~97.7 MB

// LDS map (bytes): 6 rotating bufs x 16K (tile t -> buf t%6; bufs 0,1 double
// as the x-tile buffers written by xcvt) | B1 pin 40K
#define LDS_B1   98304
#define LDS_SZ   139264

struct MP {
  const float* x;
  const u16*  W0F;      // frag(nt,kt,wn,kk): u16 off = nt*81920 + kt*8192 + wn*2048 + kk*512
  const u16*  W1F;      // frag(ntp,kt,kk): byte off = ntp*40960 + (kt*4+kk)*1024
  const float* b0;      // [4096] n = h*4+g
  const float* b1;      // [1024]
  u16*  H0;             // H0seq: 129 x [256][1024]
  u16*  H1;             // H1seq: 129 x [256][256] (== hseq, bf16)
  float* out;
  unsigned* bar;
};

__device__ __forceinline__ float sigm(float x){ return 1.f/(1.f+__expf(-x)); }
__device__ __forceinline__ float tanh_(float x){
  float t = __expf(-2.f*fabsf(x));
  float r = (1.f - t)/(1.f + t);
  return x < 0.f ? -r : r;
}
__device__ __forceinline__ u16 f2b(float v){
  __hip_bfloat16 h = __float2bfloat16(v);
  return *reinterpret_cast<u16*>(&h);
}
__device__ __forceinline__ float b2f(u16 u){
  u32 w = ((u32)u) << 16;
  return *reinterpret_cast<float*>(&w);
}
__device__ __forceinline__ void ast32(u16* p, u32 v){
  __hip_atomic_store((u32*)p, v, __ATOMIC_RELAXED, __HIP_MEMORY_SCOPE_AGENT);
}
__device__ __forceinline__ f32x4 MF(short8 a, short8 b, f32x4 c){
  return __builtin_amdgcn_mfma_f32_16x16x32_bf16(a, b, c, 0, 0, 0);
}
__device__ __forceinline__ void gll16(const void* g, void* l){
  __builtin_amdgcn_global_load_lds(
      (const __attribute__((address_space(1))) void*)g,
      (__attribute__((address_space(3))) void*)l, 16, 0, 0);
}

#define STRX(x) #x
#define PLOADO(dst, ptr, off) asm volatile("global_load_dwordx4 %0, %1, off offset:" STRX(off) : "=v"(dst) : "v"(ptr))
#define VMW(N)  do{ asm volatile("s_waitcnt vmcnt(" STRX(N) ")" ::: "memory"); __builtin_amdgcn_sched_barrier(0); }while(0)
#define BAR     do{ __builtin_amdgcn_s_barrier(); __builtin_amdgcn_sched_barrier(0); }while(0)

// ---------------- prologue kernels (unchanged) ----------------

__global__ void k_packF0(const float* __restrict__ Wx, const float* __restrict__ Wh,
                         u16* __restrict__ W0F){
  int gid = blockIdx.x*256 + threadIdx.x;       // 655360
  int F = gid >> 6, lane = gid & 63;
  int kk = F & 3, wn = (F >> 2) & 3;
  int r = F >> 4, kt = r % 10, nt = r / 10;     // nt 0..63
  int n = nt*64 + wn*16 + (lane & 15);
  int h = n >> 2, g = n & 3;
  int kb = kt*128 + kk*32 + (lane >> 4)*8;
  union { u16 u[8]; short8 v; } pk;
#pragma unroll
  for (int j = 0; j < 8; ++j) {
    int k = kb + j;
    float v = (k < 256) ? Wx[((size_t)g*256 + k)*1024 + h]
                        : Wh[((size_t)g*1024 + (k-256))*1024 + h];
    pk.u[j] = f2b(v);
  }
  *(short8*)&W0F[(size_t)F*512 + lane*8] = pk.v;
}

__global__ void k_packF1(const float* __restrict__ Wx, const float* __restrict__ Wh,
                         u16* __restrict__ W1F){
  int gid = blockIdx.x*256 + threadIdx.x;       // 163840
  int F = gid >> 6, lane = gid & 63;
  int kk = F & 3, kt = (F >> 2) % 10, ntp = F / 40;  // ntp 0..63
  int n = ntp*16 + (lane & 15);
  int h = n >> 2, g = n & 3;
  int kb = kt*128 + kk*32 + (lane >> 4)*8;
  union { u16 u[8]; short8 v; } pk;
#pragma unroll
  for (int j = 0; j < 8; ++j) {
    int k = kb + j;
    float v = (k < 1024) ? Wx[((size_t)g*1024 + k)*256 + h]
                         : Wh[((size_t)g*256 + (k-1024))*256 + h];
    pk.u[j] = f2b(v);
  }
  *(short8*)&W1F[(size_t)F*512 + lane*8] = pk.v;
}

__global__ void k_bias(const float* __restrict__ bx0, const float* __restrict__ bh0,
                       const float* __restrict__ bx1, const float* __restrict__ bh1,
                       float* __restrict__ b0, float* __restrict__ b1){
  int n = blockIdx.x*256 + threadIdx.x;
  if (n < 4096) { int h = n >> 2, g = n & 3; b0[n] = bx0[g*1024 + h] + bh0[g*1024 + h]; }
  if (n < 1024) { int h = n >> 2, g = n & 3; b1[n] = bx1[g*256 + h] + bh1[g*256 + h]; }
}

__global__ void k_init(u16* __restrict__ H0, u16* __restrict__ H1,
                       unsigned* __restrict__ bar){
  int i = blockIdx.x*256 + threadIdx.x;         // 1024 blocks -> 262144
  if (i < 262144) H0[i] = 0;                    // panel 0
  if (i < 65536)  H1[i] = 0;                    // panel 0
  if (i < BAR_DW) bar[i] = 0u;
}

// ---------------- device helpers ----------------

// x[t=g] fp32 -> bf16 into rotating bufs 0,1 (block-local), DMA-tile swizzle.
// Safe: bufs 0,1 last touched at P2 (reads) / S6,S7 (writes, landed by P2's
// VMW); xcvt runs after the epilogue's __syncthreads + arrive __syncthreads.
__device__ __forceinline__ void xcvt(const MP& p, int g, char* smem){
  const int tid = threadIdx.x;
  const int row = tid >> 3, f0 = (tid & 7) << 5;
  const int m0 = (blockIdx.x >> 6) << 6;
  const float* xs = p.x + (size_t)(m0 + row)*32768 + (size_t)g*256 + f0;
  f32x4 v0,v1,v2,v3,v4,v5,v6,v7;
  PLOADO(v0, xs, 0);  PLOADO(v1, xs, 16); PLOADO(v2, xs, 32); PLOADO(v3, xs, 48);
  PLOADO(v4, xs, 64); PLOADO(v5, xs, 80); PLOADO(v6, xs, 96); PLOADO(v7, xs, 112);
  VMW(0);
  char* xb = smem + ((f0 >> 7) << 14);          // buf0 (k 0-127) / buf1 (k 128-255)
  const int cb = (f0 & 127) >> 3, sw = row & 7;
  union { u16 u[8]; short8 s; } pk;
#define XPK(VA, VB, CC) \
  pk.u[0]=f2b(VA[0]); pk.u[1]=f2b(VA[1]); pk.u[2]=f2b(VA[2]); pk.u[3]=f2b(VA[3]); \
  pk.u[4]=f2b(VB[0]); pk.u[5]=f2b(VB[1]); pk.u[6]=f2b(VB[2]); pk.u[7]=f2b(VB[3]); \
  *(short8*)(xb + row*256 + ((((cb+(CC)) ^ sw))<<4)) = pk.s;
  XPK(v0,v1,0) XPK(v2,v3,1) XPK(v4,v5,2) XPK(v6,v7,3)
#undef XPK
}

// ---------- fused step, pair-merged phases, 6-buf rotation (t -> buf t%6) --
// Tiles: 0-1 = x (bufs 0,1; W in VGPR wpx), 2-9 = h0 (DMA; W in VGPR wp),
// 10-11 = h1 (DMA; B1 in LDS). Layer0 all waves; layer1 waves 0-3.
// vmcnt ledger (2 DMA ops/tile): pre S2..S5 (bufs 2-5) = 8 ops.
//  X: MFMA{0,1}(b0,b1) no wait (xcvt data, lgkm drained pre-fused).
//  P0: VMW(4)[S2,S3 done] BAR; issue S6,S7(b0,b1); MFMA{2,3}(b2,b3)
//  P1: VMW(4)[S4,S5] BAR; issue S8,S9(b2,b3); MFMA{4,5}(b4,b5)
//  P2: VMW(4)[S6,S7] BAR; issue S10,S11(b4,b5 -> tiles 10,11); MFMA{6,7}(b0,b1)
//  P3: VMW(4)[S8,S9] BAR; MFMA{8,9}(b2,b3)
//  P4: VMW(0) BAR; MFMA{10,11}(b4,b5)
// Write-after-read safety: every S targets a buffer whose last readers are
// separated by the BAR immediately preceding the issue (X-readers of b0,b1
// pass P0's BAR before S6,S7; P0-readers of b2,b3 pass P1's BAR; P1-readers
// of b4,b5 pass P2's BAR). Next-step pre-issue/xcvt separated by epilogue
// __syncthreads. (R14's bug: pair-merge wrote bufs read in the SAME phase.)
__device__ __forceinline__ void fused(const MP& p, int g, char* smem,
                                      float* c0, float* c1,
                                      short8* wp, short8* wpx,
                                      bool doP0, bool doP1){
  const int bid = blockIdx.x, tid = threadIdx.x;
  const int grp = bid >> 6, nt = bid & 63;
  const int m0 = grp*64, n0 = nt*64, n1 = nt*16;
  const int lane = tid & 63, wid = tid >> 6;
  const int wm = wid >> 2, wn = wid & 3;
  const int lrow = lane & 15, kgrp = lane >> 4;
  const int sw = lrow & 7;
  const int r8 = lane >> 4, c16 = lane & 15;
  const int row0 = wid*8 + r8, row1 = wid*8 + 4 + r8;
  const char* Hp = (const char*)(p.H0 + (size_t)g*262144);
  const char* h0 = Hp + (size_t)(m0+row0)*2048 + ((c16 ^ (row0 & 7))<<4);
  const char* h1 = Hp + (size_t)(m0+row1)*2048 + ((c16 ^ (row1 & 7))<<4);
  const int gB = (g > 0) ? (g-1) : 0;
  const char* HB = (const char*)(p.H1 + (size_t)gB*65536);
  const char* hB0 = HB + (size_t)(m0+row0)*512 + ((c16 ^ (row0 & 7))<<4);
  const char* hB1 = HB + (size_t)(m0+row1)*512 + ((c16 ^ (row1 & 7))<<4);
  char* d0 = smem + wid*2048;
  char* d1 = smem + wid*2048 + 1024;
  const char* b1p = smem + LDS_B1;

  f32x4 acc0 = {0,0,0,0}, acc1 = {0,0,0,0};   // layer0
  f32x4 accp = {0,0,0,0};                     // layer1

#define FS0(T) do{ const int _o = ((T)-2)*256, _bi = ((T)%6)*16384; \
    gll16(h0 + _o, d0 + _bi); gll16(h1 + _o, d1 + _bi); }while(0)
#define FS1(T) do{ const int _o = ((T)-10)*256, _bi = ((T)%6)*16384; \
    gll16(hB0 + _o, d0 + _bi); gll16(hB1 + _o, d1 + _bi); }while(0)
#define F_MFB(BP, B0_,B1_,B2_,B3_) do{ const char* _bp = (BP); short8 _a0,_a1; \
    const int _r0 = (wm*32 + lrow)*256, _r1 = _r0 + 16*256; \
    _a0 = *(const short8*)(_bp + _r0 + (((0+kgrp) ^ sw)<<4)); \
    _a1 = *(const short8*)(_bp + _r1 + (((0+kgrp) ^ sw)<<4)); \
    acc0 = MF(_a0,B0_,acc0); acc1 = MF(_a1,B0_,acc1); \
    _a0 = *(const short8*)(_bp + _r0 + (((4+kgrp) ^ sw)<<4)); \
    _a1 = *(const short8*)(_bp + _r1 + (((4+kgrp) ^ sw)<<4)); \
    acc0 = MF(_a0,B1_,acc0); acc1 = MF(_a1,B1_,acc1); \
    _a0 = *(const short8*)(_bp + _r0 + (((8+kgrp) ^ sw)<<4)); \
    _a1 = *(const short8*)(_bp + _r1 + (((8+kgrp) ^ sw)<<4)); \
    acc0 = MF(_a0,B2_,acc0); acc1 = MF(_a1,B2_,acc1); \
    _a0 = *(const short8*)(_bp + _r0 + (((12+kgrp) ^ sw)<<4)); \
    _a1 = *(const short8*)(_bp + _r1 + (((12+kgrp) ^ sw)<<4)); \
    acc0 = MF(_a0,B3_,acc0); acc1 = MF(_a1,B3_,acc1); }while(0)
#define F_MF1(BP, KT1) do{ const char* _bp = (BP); \
    const int _ro = (wid*16 + lrow)*256; short8 _a, _b; \
    _a = *(const short8*)(_bp + _ro + (((0+kgrp) ^ sw)<<4)); \
    _b = *(const short8*)(b1p + (((KT1)*4+0)<<10) + lane*16); accp = MF(_a,_b,accp); \
    _a = *(const short8*)(_bp + _ro + (((4+kgrp) ^ sw)<<4)); \
    _b = *(const short8*)(b1p + (((KT1)*4+1)<<10) + lane*16); accp = MF(_a,_b,accp); \
    _a = *(const short8*)(_bp + _ro + (((8+kgrp) ^ sw)<<4)); \
    _b = *(const short8*)(b1p + (((KT1)*4+2)<<10) + lane*16); accp = MF(_a,_b,accp); \
    _a = *(const short8*)(_bp + _ro + (((12+kgrp) ^ sw)<<4)); \
    _b = *(const short8*)(b1p + (((KT1)*4+3)<<10) + lane*16); accp = MF(_a,_b,accp); }while(0)

  // pre-issue first 4 h0 tiles -> bufs 2-5 (last read at prev P3/P4, safe)
  FS0(2); FS0(3); FS0(4); FS0(5);

  // X phase: bufs 0,1 (xcvt data) + VGPR wpx, no VMW
  if (doP0) {
    F_MFB(smem,         wpx[0], wpx[1], wpx[2], wpx[3]);
    F_MFB(smem + 16384, wpx[4], wpx[5], wpx[6], wpx[7]);
  }
  // P0: tiles 2,3 (bufs 2,3)
  VMW(4); BAR;
  FS0(6); FS0(7);                               // -> bufs 0,1 (X readers passed BAR)
  if (doP0) { F_MFB(smem + 32768, wp[0], wp[1], wp[2], wp[3]);
              F_MFB(smem + 49152, wp[4], wp[5], wp[6], wp[7]); }
  if (doP1 && wid < 4) { F_MF1(smem + 32768, 0); F_MF1(smem + 49152, 1); }
  // P1: tiles 4,5 (bufs 4,5)
  VMW(4); BAR;
  FS0(8); FS0(9);                               // -> bufs 2,3 (P0 readers passed BAR)
  if (doP0) { F_MFB(smem + 65536, wp[8], wp[9], wp[10], wp[11]);
              F_MFB(smem + 81920, wp[12], wp[13], wp[14], wp[15]); }
  if (doP1 && wid < 4) { F_MF1(smem + 65536, 2); F_MF1(smem + 81920, 3); }
  // P2: tiles 6,7 (bufs 0,1)
  VMW(4); BAR;
  FS1(10); FS1(11);                             // -> bufs 4,5 (P1 readers passed BAR)
  if (doP0) { F_MFB(smem,         wp[16], wp[17], wp[18], wp[19]);
              F_MFB(smem + 16384, wp[20], wp[21], wp[22], wp[23]); }
  if (doP1 && wid < 4) { F_MF1(smem, 4); F_MF1(smem + 16384, 5); }
  // P3: tiles 8,9 (bufs 2,3)
  VMW(4); BAR;
  if (doP0) { F_MFB(smem + 32768, wp[24], wp[25], wp[26], wp[27]);
              F_MFB(smem + 49152, wp[28], wp[29], wp[30], wp[31]); }
  if (doP1 && wid < 4) { F_MF1(smem + 32768, 6); F_MF1(smem + 49152, 7); }
  // P4: tiles 10,11 (bufs 4,5, h1)
  VMW(0); BAR;
  if (doP1 && wid < 4) { F_MF1(smem + 65536, 8); F_MF1(smem + 81920, 9); }

  // ---- merged epilogue: gl0 [64][68] f32 at smem+0, gl1 [64][20] at +20480
  __syncthreads();
  float* gl0 = (float*)smem;
  float* gl1 = (float*)(smem + 20480);
  if (doP0) {
#pragma unroll
    for (int r = 0; r < 4; ++r) {
      gl0[(wm*32      + kgrp*4 + r)*68 + wn*16 + lrow] = acc0[r];
      gl0[(wm*32 + 16 + kgrp*4 + r)*68 + wn*16 + lrow] = acc1[r];
    }
  }
  if (doP1 && wid < 4) {
#pragma unroll
    for (int r = 0; r < 4; ++r)
      gl1[(wid*16 + kgrp*4 + r)*20 + lrow] = accp[r];
  }
  __syncthreads();
  if (doP0) {
    u16* H0w = p.H0 + (size_t)(g+1)*262144;
    int bl = tid >> 3, hp = tid & 7;
    int b = m0 + bl, h = nt*16 + hp*2;
    float hn[2];
#pragma unroll
    for (int q = 0; q < 2; ++q) {
      int col = (hp*2 + q)*4;
      float gi = gl0[bl*68 + col+0] + p.b0[n0 + col+0];
      float gf = gl0[bl*68 + col+1] + p.b0[n0 + col+1];
      float go = gl0[bl*68 + col+2] + p.b0[n0 + col+2];
      float gc = gl0[bl*68 + col+3] + p.b0[n0 + col+3];
      float cn = sigm(gf)*c0[q] + sigm(gi)*tanh_(gc);
      hn[q] = sigm(go)*tanh_(cn);
      c0[q] = cn;
      if (g == TS-1) {
        p.out[OFF_H0 + (size_t)b*1024 + h + q] = hn[q];
        p.out[OFF_C0 + (size_t)b*1024 + h + q] = cn;
      }
    }
    ast32(H0w + (size_t)b*1024 + h, (u32)f2b(hn[0]) | ((u32)f2b(hn[1]) << 16));
  }
  if (doP1 && tid < 128) {
    u16* H1w = p.H1 + (size_t)g*65536;
    int bl = tid >> 1, hp = tid & 1;
    int b = m0 + bl, h = nt*4 + hp*2;
    float hn[2];
#pragma unroll
    for (int q = 0; q < 2; ++q) {
      int col = (hp*2 + q)*4;
      float gi = gl1[bl*20 + col+0] + p.b1[n1 + col+0];
      float gf = gl1[bl*20 + col+1] + p.b1[n1 + col+1];
      float go = gl1[bl*20 + col+2] + p.b1[n1 + col+2];
      float gc = gl1[bl*20 + col+3] + p.b1[n1 + col+3];
      float cn = sigm(gf)*c1[q] + sigm(gi)*tanh_(gc);
      hn[q] = sigm(go)*tanh_(cn);
      c1[q] = cn;
      if (g == TS) {
        p.out[OFF_H1 + (size_t)b*256 + h + q] = hn[q];
        p.out[OFF_C1 + (size_t)b*256 + h + q] = cn;
      }
    }
    ast32(H1w + (size_t)b*256 + h, (u32)f2b(hn[0]) | ((u32)f2b(hn[1]) << 16));
  }
}

// ---------------- main cooperative kernel ----------------
__global__ __launch_bounds__(NT, 1) void k_main(MP p){
  __shared__ __attribute__((aligned(16))) char smem[LDS_SZ];
  float c0[2] = {0.f, 0.f};
  float c1[2] = {0.f, 0.f};
  short8 wp[32];                        // pinned W0 frags, h0 tiles 2-9
  short8 wpx[8];                        // pinned W0 frags, x tiles 0-1
  const int bid = blockIdx.x, tid = threadIdx.x;
  const int grp = bid >> 6, j = bid & 63;
  const int lane = tid & 63, wid = tid >> 6;
  unsigned* flags = p.bar;
  unsigned* rel   = p.bar + 4096 + grp*16;

  // pin B1 slice in LDS (40 KB) — once
  {
    const char* wsrc = (const char*)p.W1F + (size_t)j*40960 + lane*16;
#pragma unroll
    for (int q = 0; q < 5; ++q) {
      int f = wid*5 + q;
      gll16(wsrc + f*1024, smem + LDS_B1 + f*1024);
    }
    VMW(0);
  }
  // pin W0 frags in VGPRs — once (tiles 0-1 -> wpx, 2-9 -> wp)
  {
    const u16* bb = p.W0F + (size_t)j*81920 + (wid & 3)*2048 + lane*8;
#define LDWX(T) do{ const u16* _s = bb + (size_t)(T)*8192; \
    PLOADO(wpx[(T)*4+0],_s,0); PLOADO(wpx[(T)*4+1],_s,1024); \
    PLOADO(wpx[(T)*4+2],_s,2048); PLOADO(wpx[(T)*4+3],_s,3072); }while(0)
    LDWX(0); LDWX(1);
#undef LDWX
#define LDW(T) do{ const u16* _s = bb + (size_t)(T)*8192; \
    PLOADO(wp[((T)-2)*4+0],_s,0); PLOADO(wp[((T)-2)*4+1],_s,1024); \
    PLOADO(wp[((T)-2)*4+2],_s,2048); PLOADO(wp[((T)-2)*4+3],_s,3072); }while(0)
    LDW(2); LDW(3); LDW(4); LDW(5); LDW(6); LDW(7); LDW(8); LDW(9);
#undef LDW
    VMW(0);
  }

  xcvt(p, 0, smem);
  __syncthreads();
  fused(p, 0, smem, c0, c1, wp, wpx, true, false);   // layer0 t=0 only

  for (int g = 1; g <= TS; ++g) {
    // arrive (drains sc1 h-stores), shadow-convert x[g], wait release
    __syncthreads();
    if (j == 0) {
      if (tid >= 1 && tid < 64) {
        while (__hip_atomic_load(&flags[(grp*64 + tid)*16], __ATOMIC_RELAXED,
                                 __HIP_MEMORY_SCOPE_AGENT) < (unsigned)g)
          __builtin_amdgcn_s_sleep(1);
      }
      __syncthreads();
      if (tid == 0)
        __hip_atomic_store(rel, (unsigned)g, __ATOMIC_RELAXED, __HIP_MEMORY_SCOPE_AGENT);
    } else {
      if (tid == 0)
        __hip_atomic_store(&flags[bid*16], (unsigned)g, __ATOMIC_RELAXED,
                           __HIP_MEMORY_SCOPE_AGENT);
    }
    if (g < TS) xcvt(p, g, smem);
    if (j != 0 && tid == 0) {
      while (__hip_atomic_load(rel, __ATOMIC_RELAXED, __HIP_MEMORY_SCOPE_AGENT) < (unsigned)g)
        __builtin_amdgcn_s_sleep(1);
    }
    __syncthreads();
    fused(p, g, smem, c0, c1, wp, wpx, g < TS, true);
  }
}

// ---------------- final projection (reads H1seq bf16) ----------------
__global__ void k_final_seq(const u16* __restrict__ H1seq, const float* __restrict__ Wout,
                            const float* __restrict__ bout, float* __restrict__ out){
  __shared__ float Ws[1536];
  __shared__ float bs[12];
  for (int i = threadIdx.x; i < 1536; i += 256) Ws[i] = Wout[i];
  if (threadIdx.x < 12) bs[threadIdx.x] = bout[threadIdx.x];
  __syncthreads();
  int gid = blockIdx.x*256 + threadIdx.x;
  int b = gid >> 8, ii = gid & 255;
  const u16* src = H1seq + (size_t)((ii >> 1) + 1)*65536 + b*256 + (ii & 1)*128;
  float acc[12];
#pragma unroll
  for (int k = 0; k < 12; ++k) acc[k] = bs[k];
  for (int jj = 0; jj < 128; jj += 8) {
    union { u16 u[8]; short8 v; } pk;
    pk.v = *(const short8*)&src[jj];
#pragma unroll
    for (int e = 0; e < 8; ++e) {
      float f = b2f(pk.u[e]);
#pragma unroll
      for (int k = 0; k < 12; ++k) acc[k] += f*Ws[(jj+e)*12+k];
    }
  }
  float* dst = out + (size_t)b*3072 + ii*12;
#pragma unroll
  for (int k = 0; k < 12; ++k) dst[k] = acc[k];
}

extern "C" void kernel_launch(void* const* d_in, const int* in_sizes, int n_in,
                              void* d_out, int out_size, void* d_ws, size_t ws_size,
                              hipStream_t stream) {
  if (ws_size < (size_t)WS_NEED) return;   // fail visibly if ws too small
  const float* x    = (const float*)d_in[0];
  const float* Wx0  = (const float*)d_in[1];
  const float* bx0  = (const float*)d_in[2];
  const float* Wh0  = (const float*)d_in[3];
  const float* bh0  = (const float*)d_in[4];
  const float* Wx1  = (const float*)d_in[5];
  const float* bx1  = (const float*)d_in[6];
  const float* Wh1  = (const float*)d_in[7];
  const float* bh1  = (const float*)d_in[8];
  const float* Wout = (const float*)d_in[9];
  const float* bout = (const float*)d_in[10];

  char* ws = (char*)d_ws;
  u16*   W0F  = (u16*)  (ws + WSO_W0F);
  u16*   W1F  = (u16*)  (ws + WSO_W1F);
  float* b0   = (float*)(ws + WSO_B0);
  float* b1   = (float*)(ws + WSO_B1);
  unsigned* bar = (unsigned*)(ws + WSO_BAR);
  u16*   H0   = (u16*)  (ws + WSO_H0);
  u16*   H1   = (u16*)  (ws + WSO_H1);
  float* out = (float*)d_out;

  k_packF0<<<2560, 256, 0, stream>>>(Wx0, Wh0, W0F);
  k_packF1<<<640, 256, 0, stream>>>(Wx1, Wh1, W1F);
  k_bias<<<16, 256, 0, stream>>>(bx0, bh0, bx1, bh1, b0, b1);
  k_init<<<1024, 256, 0, stream>>>(H0, H1, bar);

  MP p;
  p.x = x; p.W0F = W0F; p.W1F = W1F; p.b0 = b0; p.b1 = b1;
  p.H0 = H0; p.H1 = H1; p.out = out; p.bar = bar;
  void* kargs[] = { (void*)&p };
  hipLaunchCooperativeKernel((const void*)k_main, dim3(NB), dim3(NT), kargs, 0, stream);

  k_final_seq<<<256, 256, 0, stream>>>(H1, Wout, bout, out);
}